// Round 1
// baseline (54.973 us; speedup 1.0000x reference)
//
#include <hip/hip_runtime.h>

#define BLOCK 256
#define GRID  2048

// _S = 0.7071 (python double -> f32, identical to 0.7071f)
__device__ __constant__ float c_dirs[26][3] = {
    {0.f,0.f,1.f},        {0.f,0.f,-1.f},       {0.f,-0.7071f,0.7071f}, {0.f,-1.f,0.f},
    {0.f,-0.7071f,-0.7071f},{0.f,0.7071f,-0.7071f},{0.f,1.f,0.f},        {0.f,0.7071f,0.7071f},
    {0.7071f,0.f,0.7071f},{1.f,0.f,0.f},        {0.7071f,0.f,-0.7071f},{-0.7071f,0.f,-0.7071f},
    {-1.f,0.f,0.f},       {-0.7071f,0.f,0.7071f},{0.5f,-0.7071f,0.5f},  {-0.5f,-0.7071f,-0.5f},
    {-0.5f,0.7071f,-0.5f},{0.5f,0.7071f,0.5f},  {0.7071f,-0.7071f,0.f},{-0.7071f,-0.7071f,0.f},
    {-0.7071f,0.7071f,0.f},{0.7071f,0.7071f,0.f},{0.5f,-0.7071f,-0.5f},{-0.5f,-0.7071f,0.5f},
    {-0.5f,0.7071f,0.5f}, {0.5f,0.7071f,-0.5f}};

// Per-row combined loss: 0.5 * W2[argmax(x), t] + 0.5 * (lse - (C0*sum(x) + 0.996*x[t]))
// where eps = 0.1/26, C0 = eps/25, and (1-eps) - C0 = 0.996 exactly.
__global__ __launch_bounds__(BLOCK) void cmdce_main(const float* __restrict__ x,
                                                    const int* __restrict__ tgt,
                                                    double* __restrict__ acc_out,
                                                    int B) {
    __shared__ float w2[26 * 26];
    for (int idx = threadIdx.x; idx < 676; idx += BLOCK) {
        int p = idx / 26, t = idx - p * 26;
        float px = c_dirs[p][0], py = c_dirs[p][1], pz = c_dirs[p][2];
        float qx = c_dirs[t][0], qy = c_dirs[t][1], qz = c_dirs[t][2];
        float np_ = fmaxf(sqrtf(px*px + py*py + pz*pz), 1e-8f);
        float nq_ = fmaxf(sqrtf(qx*qx + qy*qy + qz*qz), 1e-8f);
        float cosv = (px*qx + py*qy + pz*qz) / (np_ * nq_);
        float w = 1.0f - cosv;
        w2[idx] = w * w;
    }
    __syncthreads();

    const float2* x2 = reinterpret_cast<const float2*>(x);
    float acc = 0.0f;
    int tid = blockIdx.x * BLOCK + threadIdx.x;
    int stride = GRID * BLOCK;
    for (int r = tid; r < B; r += stride) {
        float v[26];
        const float2* row = x2 + (size_t)r * 13;
        #pragma unroll
        for (int k = 0; k < 13; ++k) {
            float2 p = row[k];
            v[2 * k] = p.x;
            v[2 * k + 1] = p.y;
        }
        // argmax, first-index-wins (strict >)
        float m = v[0];
        int am = 0;
        #pragma unroll
        for (int j = 1; j < 26; ++j) {
            if (v[j] > m) { m = v[j]; am = j; }
        }
        float se = 0.0f, sx = 0.0f;
        #pragma unroll
        for (int j = 0; j < 26; ++j) {
            se += __expf(v[j] - m);
            sx += v[j];
        }
        int t = tgt[r];
        // x[t] without runtime-indexing the register array (avoid scratch)
        float xt = 0.0f;
        #pragma unroll
        for (int j = 0; j < 26; ++j) xt = (j == t) ? v[j] : xt;

        float ce = m + __logf(se) - (1.5384615384615385e-4f * sx + 0.996f * xt);
        float dd = w2[am * 26 + t];
        acc += 0.5f * (dd + ce);
    }

    // wave (64) shuffle reduction, then cross-wave via LDS, one double atomic per block
    #pragma unroll
    for (int off = 32; off > 0; off >>= 1) acc += __shfl_down(acc, off);
    __shared__ float wsum[BLOCK / 64];
    int lane = threadIdx.x & 63, wid = threadIdx.x >> 6;
    if (lane == 0) wsum[wid] = acc;
    __syncthreads();
    if (threadIdx.x == 0) {
        float s = 0.0f;
        #pragma unroll
        for (int w = 0; w < BLOCK / 64; ++w) s += wsum[w];
        atomicAdd(acc_out, (double)s);
    }
}

__global__ void cmdce_final(const double* __restrict__ acc, float* __restrict__ out, int B) {
    out[0] = (float)(acc[0] / (double)B);
}

extern "C" void kernel_launch(void* const* d_in, const int* in_sizes, int n_in,
                              void* d_out, int out_size, void* d_ws, size_t ws_size,
                              hipStream_t stream) {
    const float* x   = (const float*)d_in[0];
    const int*   tgt = (const int*)d_in[1];
    float*  out = (float*)d_out;
    double* acc = (double*)d_ws;
    int B = in_sizes[1];  // 2,000,000 rows

    hipMemsetAsync(d_ws, 0, sizeof(double), stream);
    cmdce_main<<<GRID, BLOCK, 0, stream>>>(x, tgt, acc, B);
    cmdce_final<<<1, 1, 0, stream>>>(acc, out, B);
}

// Round 3
// 40.328 us; speedup vs baseline: 1.3632x; 1.3632x over previous
//
#include <hip/hip_runtime.h>

#define BLOCK  256
#define ROWS   256            // rows staged per chunk
#define GRID   1280           // 5 blocks/CU (LDS-limited) x 256 CU
#define NCLASS 26

__device__ __constant__ float c_dirs[26][3] = {
    {0.f,0.f,1.f},        {0.f,0.f,-1.f},       {0.f,-0.7071f,0.7071f}, {0.f,-1.f,0.f},
    {0.f,-0.7071f,-0.7071f},{0.f,0.7071f,-0.7071f},{0.f,1.f,0.f},        {0.f,0.7071f,0.7071f},
    {0.7071f,0.f,0.7071f},{1.f,0.f,0.f},        {0.7071f,0.f,-0.7071f},{-0.7071f,0.f,-0.7071f},
    {-1.f,0.f,0.f},       {-0.7071f,0.f,0.7071f},{0.5f,-0.7071f,0.5f},  {-0.5f,-0.7071f,-0.5f},
    {-0.5f,0.7071f,-0.5f},{0.5f,0.7071f,0.5f},  {0.7071f,-0.7071f,0.f},{-0.7071f,-0.7071f,0.f},
    {-0.7071f,0.7071f,0.f},{0.7071f,0.7071f,0.f},{0.5f,-0.7071f,-0.5f},{-0.5f,-0.7071f,0.5f},
    {-0.5f,0.7071f,0.5f}, {0.5f,0.7071f,-0.5f}};

// Per-row loss: 0.5 * W2[argmax(x), t] + 0.5 * (lse - (C0*sum(x) + 0.996*x[t]))
// eps = 0.1/26, C0 = eps/25, (1-eps) - C0 = 0.996 exactly.
__global__ __launch_bounds__(BLOCK) void cmdce_main(const float* __restrict__ x,
                                                    const int* __restrict__ tgt,
                                                    double* __restrict__ partial,
                                                    int B) {
    __shared__ float stage[ROWS * NCLASS];   // 26,624 B
    __shared__ float w2[26 * 26];            //  2,704 B
    __shared__ float wsum[BLOCK / 64];

    for (int idx = threadIdx.x; idx < 676; idx += BLOCK) {
        int p = idx / 26, t = idx - p * 26;
        float px = c_dirs[p][0], py = c_dirs[p][1], pz = c_dirs[p][2];
        float qx = c_dirs[t][0], qy = c_dirs[t][1], qz = c_dirs[t][2];
        float np_ = fmaxf(sqrtf(px*px + py*py + pz*pz), 1e-8f);
        float nq_ = fmaxf(sqrtf(qx*qx + qy*qy + qz*qz), 1e-8f);
        float cosv = (px*qx + py*qy + pz*qz) / (np_ * nq_);
        float w = 1.0f - cosv;
        w2[idx] = w * w;
    }

    const float4* src = reinterpret_cast<const float4*>(x);
    float4* stage4 = reinterpret_cast<float4*>(stage);
    float acc = 0.0f;

    int nchunks = (B + ROWS - 1) / ROWS;
    for (int c = blockIdx.x; c < nchunks; c += GRID) {
        int row0 = c * ROWS;
        int rows_in = min(ROWS, B - row0);
        int nvec = rows_in * NCLASS / 4;               // multiple of 64 here
        size_t vbase = (size_t)c * (ROWS * NCLASS / 4);
        __syncthreads();                                // w2 ready (iter 0) / prev compute done
        for (int i = threadIdx.x; i < nvec; i += BLOCK)
            stage4[i] = src[vbase + i];
        __syncthreads();

        if ((int)threadIdx.x < rows_in) {
            int r = row0 + threadIdx.x;
            float v[26];
            const float2* rowp = reinterpret_cast<const float2*>(&stage[threadIdx.x * NCLASS]);
            #pragma unroll
            for (int k = 0; k < 13; ++k) {
                float2 p = rowp[k];
                v[2 * k] = p.x;
                v[2 * k + 1] = p.y;
            }
            float m = v[0];
            int am = 0;
            #pragma unroll
            for (int j = 1; j < 26; ++j)
                if (v[j] > m) { m = v[j]; am = j; }     // first-index-wins (strict >)
            float se = 0.0f, sx = 0.0f;
            #pragma unroll
            for (int j = 0; j < 26; ++j) {
                se += __expf(v[j] - m);
                sx += v[j];
            }
            int t = tgt[r];
            float xt = 0.0f;                            // no runtime reg-array index
            #pragma unroll
            for (int j = 0; j < 26; ++j) xt = (j == t) ? v[j] : xt;

            float ce = m + __logf(se) - (1.5384615384615385e-4f * sx + 0.996f * xt);
            acc += 0.5f * (w2[am * 26 + t] + ce);
        }
    }

    // wave shuffle reduce -> cross-wave LDS -> one double store per block
    #pragma unroll
    for (int off = 32; off > 0; off >>= 1) acc += __shfl_down(acc, off);
    int lane = threadIdx.x & 63, wid = threadIdx.x >> 6;
    __syncthreads();
    if (lane == 0) wsum[wid] = acc;
    __syncthreads();
    if (threadIdx.x == 0) {
        float s = 0.0f;
        #pragma unroll
        for (int w = 0; w < BLOCK / 64; ++w) s += wsum[w];
        partial[blockIdx.x] = (double)s;
    }
}

__global__ __launch_bounds__(BLOCK) void cmdce_final(const double* __restrict__ partial,
                                                     float* __restrict__ out, int B, int n) {
    __shared__ double wsum[BLOCK / 64];
    double a = 0.0;
    for (int i = threadIdx.x; i < n; i += BLOCK) a += partial[i];
    #pragma unroll
    for (int off = 32; off > 0; off >>= 1) a += __shfl_down(a, off);
    int lane = threadIdx.x & 63, wid = threadIdx.x >> 6;
    if (lane == 0) wsum[wid] = a;
    __syncthreads();
    if (threadIdx.x == 0) {
        double s = 0.0;
        #pragma unroll
        for (int w = 0; w < BLOCK / 64; ++w) s += wsum[w];
        out[0] = (float)(s / (double)B);
    }
}

extern "C" void kernel_launch(void* const* d_in, const int* in_sizes, int n_in,
                              void* d_out, int out_size, void* d_ws, size_t ws_size,
                              hipStream_t stream) {
    const float* x   = (const float*)d_in[0];
    const int*   tgt = (const int*)d_in[1];
    float*  out = (float*)d_out;
    double* partial = (double*)d_ws;
    int B = in_sizes[1];  // 2,000,000 rows

    cmdce_main<<<GRID, BLOCK, 0, stream>>>(x, tgt, partial, B);
    cmdce_final<<<1, BLOCK, 0, stream>>>(partial, out, B, GRID);
}